// Round 1
// baseline (90.100 us; speedup 1.0000x reference)
//
#include <hip/hip_runtime.h>
#include <math.h>

#define NE 16       // experts
#define WPE 40      // packed floats per expert (160 B, 16B-aligned)

// Packed per-expert layout (floats):
//  [0:12)  A  (3x4 row-major: rows = rho,phi,theta contributions)
//  [12:28) B  (4x4 row-major: rows = cos_t, sin_t, silu(cos_t), silu(sin_t))
//  [28:32) bf (4)
//  [32:35) center (3)
//  [35] cos(tb1)  [36] sin(tb1)  [37] cos(tb2)  [38] sin(tb2)  [39] pad

__global__ void moe_prep_kernel(const float* __restrict__ proj,
                                const float* __restrict__ center,
                                const float* __restrict__ tb1,
                                const float* __restrict__ tb2,
                                const float* __restrict__ W1,
                                const float* __restrict__ Wf,
                                const float* __restrict__ bf,
                                float* __restrict__ tbl) {
    int t = threadIdx.x;
    if (t >= NE * 4) return;
    int e = t >> 2, d = t & 3;

    // M = W1[e] (12x32) @ Wf[e] (32x4), column d
    float M[12];
    #pragma unroll
    for (int i = 0; i < 12; ++i) {
        float s = 0.f;
        const float* w1r = W1 + ((e * 12 + i) * 32);
        const float* wfc = Wf + (e * 32 * 4) + d;
        #pragma unroll
        for (int k = 0; k < 32; ++k) s = fmaf(w1r[k], wfc[k * 4], s);
        M[i] = s;
    }
    float* o = tbl + e * WPE;
    // A[j][d] = sum_{i<8} proj[e][j][i] * M[i][d]
    #pragma unroll
    for (int j = 0; j < 3; ++j) {
        float s = 0.f;
        const float* pr = proj + e * 24 + j * 8;
        #pragma unroll
        for (int i = 0; i < 8; ++i) s = fmaf(pr[i], M[i], s);
        o[j * 4 + d] = s;
    }
    #pragma unroll
    for (int i = 0; i < 4; ++i) o[12 + i * 4 + d] = M[8 + i];
    o[28 + d] = bf[e * 4 + d];
    if (d == 0) {
        o[32] = center[e * 3 + 0];
        o[33] = center[e * 3 + 1];
        o[34] = center[e * 3 + 2];
        o[35] = cosf(tb1[e]);
        o[36] = sinf(tb1[e]);
        o[37] = cosf(tb2[e]);
        o[38] = sinf(tb2[e]);
        o[39] = 0.f;
    }
}

__global__ __launch_bounds__(256) void moe_main_kernel(
        const float4* __restrict__ xyzt,
        const float* __restrict__ Wg,
        const float* __restrict__ bg,
        const float* __restrict__ tbl,
        float4* __restrict__ out, int n) {
    __shared__ float lds[NE * WPE];
    for (int i = threadIdx.x; i < NE * WPE; i += 256) lds[i] = tbl[i];
    __syncthreads();

    int idx = blockIdx.x * 256 + threadIdx.x;
    if (idx >= n) return;
    float4 p = xyzt[idx];

    // ---- gating: logits = x @ Wg + bg (Wg/bg uniform -> SGPR) ----
    float logits[NE];
    #pragma unroll
    for (int e = 0; e < NE; ++e) {
        logits[e] = fmaf(p.x, Wg[e],
                    fmaf(p.y, Wg[NE + e],
                    fmaf(p.z, Wg[2 * NE + e],
                    fmaf(p.w, Wg[3 * NE + e], bg[e]))));
    }
    // top-2 (descending, ties -> lower index, matches lax.top_k)
    float best = logits[0]; int bi = 0;
    float second = -INFINITY; int si = 0;
    #pragma unroll
    for (int e = 1; e < NE; ++e) {
        float l = logits[e];
        if (l > best)        { second = best; si = bi; best = l; bi = e; }
        else if (l > second) { second = l; si = e; }
    }
    // softmax over [best, second]
    float ed = expf(second - best);
    float w0 = 1.f / (1.f + ed);
    float w1 = ed * w0;

    float st, ct;
    sincosf(p.w, &st, &ct);

    int   sel[2] = { bi, si };
    float wgt[2] = { w0, w1 };
    float acc0 = 0.f, acc1 = 0.f, acc2 = 0.f, acc3 = 0.f;

    #pragma unroll
    for (int kk = 0; kk < 2; ++kk) {
        const float* w = lds + sel[kk] * WPE;
        float cx = w[32], cy = w[33], cz = w[34];
        float xc0 = p.x - cx, xc1 = p.y - cy, xc2 = p.z - cz;
        float rho = sqrtf(fmaf(xc0, xc0, fmaf(xc1, xc1, xc2 * xc2)));
        float phi = atan2f(xc1, xc0);
        float a = xc2 / (rho + 1e-6f);
        a = fminf(1.f, fmaxf(-1.f, a));
        float theta = acosf(a);
        // cos(t+tb1), sin(t+tb2) via angle addition with precomputed sin/cos(tb)
        float cos_t = fmaf(ct, w[35], -st * w[36]);
        float sin_t = fmaf(st, w[37],  ct * w[38]);
        float silc = cos_t / (1.f + expf(-cos_t));
        float sils = sin_t / (1.f + expf(-sin_t));
        float ww = wgt[kk];
        #pragma unroll
        for (int d = 0; d < 4; ++d) {
            float o = fmaf(rho,   w[0 + d],
                      fmaf(phi,   w[4 + d],
                      fmaf(theta, w[8 + d],
                      fmaf(cos_t, w[12 + d],
                      fmaf(sin_t, w[16 + d],
                      fmaf(silc,  w[20 + d],
                      fmaf(sils,  w[24 + d], w[28 + d])))))));
            if (d == 0) acc0 = fmaf(ww, o, acc0);
            if (d == 1) acc1 = fmaf(ww, o, acc1);
            if (d == 2) acc2 = fmaf(ww, o, acc2);
            if (d == 3) acc3 = fmaf(ww, o, acc3);
        }
    }
    out[idx] = make_float4(acc0, acc1, acc2, acc3);
}

extern "C" void kernel_launch(void* const* d_in, const int* in_sizes, int n_in,
                              void* d_out, int out_size, void* d_ws, size_t ws_size,
                              hipStream_t stream) {
    const float* xyzt   = (const float*)d_in[0];
    const float* Wg     = (const float*)d_in[1];
    const float* bg     = (const float*)d_in[2];
    const float* proj   = (const float*)d_in[3];
    const float* center = (const float*)d_in[4];
    const float* tb1    = (const float*)d_in[5];
    const float* tb2    = (const float*)d_in[6];
    const float* W1     = (const float*)d_in[7];
    const float* Wf     = (const float*)d_in[8];
    const float* bf     = (const float*)d_in[9];
    float* tbl = (float*)d_ws;   // needs NE*WPE*4 = 2560 B
    int n = in_sizes[0] / 4;

    moe_prep_kernel<<<1, 64, 0, stream>>>(proj, center, tb1, tb2, W1, Wf, bf, tbl);
    moe_main_kernel<<<(n + 255) / 256, 256, 0, stream>>>(
        (const float4*)xyzt, Wg, bg, tbl, (float4*)d_out, n);
}

// Round 2
// 86.295 us; speedup vs baseline: 1.0441x; 1.0441x over previous
//
#include <hip/hip_runtime.h>
#include <math.h>

#define NE 16       // experts
#define WPE 44      // packed floats per expert (176 B). 176/16=11 quads -> expert
                    // quad-offset e*11 mod 8 = e*3 mod 8 covers all 8 bank-quads:
                    // near-conflict-free ds_read_b128 gather across lanes.

// Packed per-expert layout (float index base = e*WPE):
//  [0:32)  8 rows x float4: output weights for features
//          [rho, phi, theta, cos_t, sin_t, silu(cos_t), silu(sin_t), 1]
//          (row 7 = bf bias, feature == 1)
//  [32:36) cx, cy, cz, cos(tb1)
//  [36:40) sin(tb1), cos(tb2), sin(tb2), 0
//  [40:44) pad

__global__ __launch_bounds__(256) void moe_prep_kernel(
        const float* __restrict__ proj,
        const float* __restrict__ center,
        const float* __restrict__ tb1,
        const float* __restrict__ tb2,
        const float* __restrict__ W1,
        const float* __restrict__ Wf,
        const float* __restrict__ bf,
        float* __restrict__ tbl) {
    __shared__ float Msh[NE * 48];       // M[e][i*4+d], i<12
    int t = threadIdx.x;
    {
        int e = t >> 4, l = t & 15;      // 16 threads per expert, 3 dots each
        #pragma unroll
        for (int k = 0; k < 3; ++k) {
            int j = l + k * 16;          // 0..47
            int i = j >> 2, d = j & 3;
            const float* w1r = W1 + (e * 12 + i) * 32;
            const float* wfc = Wf + e * 128 + d;
            float s = 0.f;
            #pragma unroll
            for (int q = 0; q < 32; ++q) s = fmaf(w1r[q], wfc[q * 4], s);
            Msh[e * 48 + j] = s;
        }
    }
    __syncthreads();
    if (t < NE * 4) {
        int e = t >> 2, d = t & 3;
        const float* Me = Msh + e * 48;
        float* o = tbl + e * WPE;
        // rows 0..2: fold proj into M[0:8]  (A = proj_e @ M[0:8])
        #pragma unroll
        for (int j = 0; j < 3; ++j) {
            float s = 0.f;
            const float* pr = proj + e * 24 + j * 8;
            #pragma unroll
            for (int i = 0; i < 8; ++i) s = fmaf(pr[i], Me[i * 4 + d], s);
            o[j * 4 + d] = s;
        }
        // rows 3..6: temb weights = M[8:12]
        #pragma unroll
        for (int i = 0; i < 4; ++i) o[(3 + i) * 4 + d] = Me[(8 + i) * 4 + d];
        // row 7: bias
        o[7 * 4 + d] = bf[e * 4 + d];
        if (d == 0) {
            o[32] = center[e * 3 + 0];
            o[33] = center[e * 3 + 1];
            o[34] = center[e * 3 + 2];
            o[35] = cosf(tb1[e]);
            o[36] = sinf(tb1[e]);
            o[37] = cosf(tb2[e]);
            o[38] = sinf(tb2[e]);
            o[39] = 0.f; o[40] = 0.f; o[41] = 0.f; o[42] = 0.f; o[43] = 0.f;
        }
    }
}

__device__ __forceinline__ float fast_rcp(float x) {
    return __builtin_amdgcn_rcpf(x);     // v_rcp_f32, ~1 ulp
}

__device__ __forceinline__ float4 f4fma(float s, float4 a, float4 b) {
    return make_float4(fmaf(s, a.x, b.x), fmaf(s, a.y, b.y),
                       fmaf(s, a.z, b.z), fmaf(s, a.w, b.w));
}

// minimax atan2, max err ~3e-6 rad (branch-free quadrant fixup)
__device__ __forceinline__ float fast_atan2f(float y, float x) {
    float ax = fabsf(x), ay = fabsf(y);
    float mx = fmaxf(ax, ay), mn = fminf(ax, ay);
    float r = mn * fast_rcp(fmaxf(mx, 1e-37f));
    float s = r * r;
    float p =              -0.0117212f;
    p = fmaf(p, s,  0.05265332f);
    p = fmaf(p, s, -0.11643287f);
    p = fmaf(p, s,  0.19354346f);
    p = fmaf(p, s, -0.33262347f);
    p = fmaf(p, s,  0.99997726f);
    float a = r * p;
    a = (ay > ax) ? (1.57079637f - a) : a;
    a = (x < 0.f) ? (3.14159274f - a) : a;
    return copysignf(a, y);
}

// A&S 4.4.45 acos, max err ~1.8e-4 rad (output budget is 0.17 abs)
__device__ __forceinline__ float fast_acosf(float x) {
    float ax = fminf(fabsf(x), 1.f);
    float p = fmaf(ax, -0.0187293f, 0.0742610f);
    p = fmaf(p, ax, -0.2121144f);
    p = fmaf(p, ax, 1.5707288f);
    float r = sqrtf(1.f - ax) * p;
    return (x >= 0.f) ? r : (3.14159274f - r);
}

__global__ __launch_bounds__(256) void moe_main_kernel(
        const float4* __restrict__ xyzt,
        const float* __restrict__ Wg,
        const float* __restrict__ bg,
        const float* __restrict__ tbl,
        float4* __restrict__ out, int n) {
    __shared__ float lds[NE * WPE];
    for (int i = threadIdx.x; i < NE * WPE; i += 256) lds[i] = tbl[i];
    __syncthreads();

    int idx = blockIdx.x * 256 + threadIdx.x;
    if (idx >= n) return;
    float4 p = xyzt[idx];

    // ---- gating: logits = x @ Wg + bg (Wg/bg uniform -> s_loads) ----
    float logits[NE];
    #pragma unroll
    for (int e = 0; e < NE; ++e) {
        logits[e] = fmaf(p.x, Wg[e],
                    fmaf(p.y, Wg[NE + e],
                    fmaf(p.z, Wg[2 * NE + e],
                    fmaf(p.w, Wg[3 * NE + e], bg[e]))));
    }
    // top-2 (descending; strict > keeps lower index on ties, matching top_k)
    float best = logits[0]; int bi = 0;
    float second = -INFINITY; int si = 0;
    #pragma unroll
    for (int e = 1; e < NE; ++e) {
        float l = logits[e];
        if (l > best)        { second = best; si = bi; best = l; bi = e; }
        else if (l > second) { second = l; si = e; }
    }
    // softmax over the pair
    float ed = __expf(second - best);
    float w0 = fast_rcp(1.f + ed);
    float w1 = ed * w0;

    float st, ct;
    __sincosf(p.w, &st, &ct);

    int   sel[2] = { bi, si };
    float wgt[2] = { w0, w1 };
    float4 acc = make_float4(0.f, 0.f, 0.f, 0.f);

    #pragma unroll
    for (int kk = 0; kk < 2; ++kk) {
        const float4* w4 = (const float4*)(lds + sel[kk] * WPE); // 176B-aligned
        float4 cc = w4[8];   // cx, cy, cz, cos(tb1)
        float4 ss = w4[9];   // sin(tb1), cos(tb2), sin(tb2), 0
        float xc0 = p.x - cc.x, xc1 = p.y - cc.y, xc2 = p.z - cc.z;
        float rho = sqrtf(fmaf(xc0, xc0, fmaf(xc1, xc1, xc2 * xc2)));
        float phi = fast_atan2f(xc1, xc0);
        float theta = fast_acosf(xc2 * fast_rcp(rho + 1e-6f));
        // cos(t+tb1), sin(t+tb2) via angle addition
        float cos_t = fmaf(ct, cc.w, -st * ss.x);
        float sin_t = fmaf(st, ss.y,  ct * ss.z);
        float silc = cos_t * fast_rcp(1.f + __expf(-cos_t));
        float sils = sin_t * fast_rcp(1.f + __expf(-sin_t));

        float4 r = w4[7];                  // bias row
        r = f4fma(rho,   w4[0], r);
        r = f4fma(phi,   w4[1], r);
        r = f4fma(theta, w4[2], r);
        r = f4fma(cos_t, w4[3], r);
        r = f4fma(sin_t, w4[4], r);
        r = f4fma(silc,  w4[5], r);
        r = f4fma(sils,  w4[6], r);
        acc = f4fma(wgt[kk], r, acc);
    }
    out[idx] = acc;
}

extern "C" void kernel_launch(void* const* d_in, const int* in_sizes, int n_in,
                              void* d_out, int out_size, void* d_ws, size_t ws_size,
                              hipStream_t stream) {
    const float* xyzt   = (const float*)d_in[0];
    const float* Wg     = (const float*)d_in[1];
    const float* bg     = (const float*)d_in[2];
    const float* proj   = (const float*)d_in[3];
    const float* center = (const float*)d_in[4];
    const float* tb1    = (const float*)d_in[5];
    const float* tb2    = (const float*)d_in[6];
    const float* W1     = (const float*)d_in[7];
    const float* Wf     = (const float*)d_in[8];
    const float* bf     = (const float*)d_in[9];
    float* tbl = (float*)d_ws;   // NE*WPE*4 = 2816 B of scratch
    int n = in_sizes[0] / 4;

    moe_prep_kernel<<<1, 256, 0, stream>>>(proj, center, tb1, tb2, W1, Wf, bf, tbl);
    moe_main_kernel<<<(n + 255) / 256, 256, 0, stream>>>(
        (const float4*)xyzt, Wg, bg, tbl, (float4*)d_out, n);
}